// Round 10
// baseline (114.371 us; speedup 1.0000x reference)
//
#include <hip/hip_runtime.h>
#include <math.h>

#define PI_F        3.14159265358979323846f
#define TWO_PI_F    6.2831853071795864769f
#define INV_TWO_PI_F 0.15915494309189533577f

typedef __attribute__((ext_vector_type(8))) short  bf16x8;
typedef __attribute__((ext_vector_type(8))) __bf16 bf16v8;
typedef __attribute__((ext_vector_type(4))) float  f32x4;

__device__ __forceinline__ bf16x8 cvt8(f32x4 a, f32x4 b) {
    bf16v8 v;
    v[0] = (__bf16)a.x; v[1] = (__bf16)a.y; v[2] = (__bf16)a.z; v[3] = (__bf16)a.w;
    v[4] = (__bf16)b.x; v[5] = (__bf16)b.y; v[6] = (__bf16)b.z; v[7] = (__bf16)b.w;
    return __builtin_bit_cast(bf16x8, v);
}

// ------------------------------------------------------------------
// W prep: convert W (f32 [64][256]) into bf16 MFMA B-fragment layout:
// wfb[level][(nt4*8+ks)*64 + lane] = W[nt4*16+(l&15)][ks*32+(l>>4)*8 ..+8]
// (nt4 = global 16-col tile 0..3). One 16B fragment per thread.
// ------------------------------------------------------------------
__global__ __launch_bounds__(256) void wprep(
    const float* __restrict__ W0, const float* __restrict__ W1,
    const float* __restrict__ W2, __bf16* __restrict__ wfb)
{
    const int level = blockIdx.x >> 3;
    const int rem   = ((blockIdx.x & 7) << 8) | threadIdx.x;   // 0..2047
    const float* W  = level == 0 ? W0 : (level == 1 ? W1 : W2);
    const int l   = rem & 63;
    const int ks  = (rem >> 6) & 7;
    const int nt4 = rem >> 9;
    const int col = nt4 * 16 + (l & 15);
    const int k0  = ks * 32 + (l >> 4) * 8;
    const float* wp = W + col * 256 + k0;
    bf16x8 f = cvt8(*(const f32x4*)wp, *(const f32x4*)(wp + 4));
    *(bf16x8*)(wfb + (size_t)level * 16384 + (size_t)rem * 8) = f;
}

// ------------------------------------------------------------------
// Register-direct bf16-MFMA GEMM (no LDS, no barriers): y = x (.) W^T,
// K=256, Do=64, y stored bf16. 256 thr = 4 waves (2 row-halves x 2
// col-halves); each wave independently computes 32 rows x 32 cols:
//   - wf[2][8] B-frags from prepped array (contiguous 16B loads)
//   - A-frags loaded DIRECTLY from global x (lanes {m,m+16,m+32,m+48}
//     cover row m bytes {0,32,64,96}+16 of a 128B span -> full-line
//     coalescing), converted f32->bf16 inline
//   - 32 MFMA 16x16x32, acc[2][2], all scheduling left to the compiler
//     (no sync -> free software pipelining + TLP across ~8-12 waves/CU).
// MFMA 16x16x32: A(m,k): lane=(k>>3)*16+m, slots k&7.
//                B(k,n): lane=(k>>3)*16+n.
//                C(m,n): n=lane&15, m=(lane>>4)*4+reg.
// ------------------------------------------------------------------
__device__ __forceinline__ void gemm_body(
    int bid,
    const float* __restrict__ x, const __bf16* __restrict__ wfb,
    __bf16* __restrict__ y)
{
    const int tid  = threadIdx.x;
    const int lane = tid & 63;
    const int w    = tid >> 6;
    const int wm   = w >> 1;                 // row half
    const int wn   = w & 1;                  // col half
    const int l16  = lane & 15;
    const int lq   = lane >> 4;
    const long r0  = (long)bid * 64 + wm * 32;

    // ---- B-frags: wave's 32 cols = n-tiles wn*2, wn*2+1
    bf16x8 wf[2][8];
    #pragma unroll
    for (int nt = 0; nt < 2; ++nt) {
        const __bf16* wb = wfb + (size_t)(wn * 2 + nt) * 4096 + (size_t)lane * 8;
        #pragma unroll
        for (int ks = 0; ks < 8; ++ks)
            wf[nt][ks] = *(const bf16x8*)(wb + ks * 512);
    }

    f32x4 acc[2][2];
    #pragma unroll
    for (int mt = 0; mt < 2; ++mt)
        #pragma unroll
        for (int nt = 0; nt < 2; ++nt)
            acc[mt][nt] = f32x4{0.f, 0.f, 0.f, 0.f};

    const float* xr0 = x + (r0 + l16) * 256 + lq * 8;        // m-tile 0
    const float* xr1 = xr0 + 16 * 256;                       // m-tile 1

    #pragma unroll
    for (int ks = 0; ks < 8; ++ks) {
        bf16x8 a0 = cvt8(*(const f32x4*)(xr0 + ks * 32),
                         *(const f32x4*)(xr0 + ks * 32 + 4));
        bf16x8 a1 = cvt8(*(const f32x4*)(xr1 + ks * 32),
                         *(const f32x4*)(xr1 + ks * 32 + 4));
        acc[0][0] = __builtin_amdgcn_mfma_f32_16x16x32_bf16(a0, wf[0][ks], acc[0][0], 0, 0, 0);
        acc[0][1] = __builtin_amdgcn_mfma_f32_16x16x32_bf16(a0, wf[1][ks], acc[0][1], 0, 0, 0);
        acc[1][0] = __builtin_amdgcn_mfma_f32_16x16x32_bf16(a1, wf[0][ks], acc[1][0], 0, 0, 0);
        acc[1][1] = __builtin_amdgcn_mfma_f32_16x16x32_bf16(a1, wf[1][ks], acc[1][1], 0, 0, 0);
    }

    // ---- store: C(m,n): n = lane&15, m = (lane>>4)*4 + j; bf16
    #pragma unroll
    for (int mt = 0; mt < 2; ++mt) {
        const long rr = r0 + mt * 16 + lq * 4;
        #pragma unroll
        for (int nt = 0; nt < 2; ++nt) {
            const int col = wn * 32 + nt * 16 + l16;
            #pragma unroll
            for (int j = 0; j < 4; ++j)
                y[(rr + j) * 64 + col] = (__bf16)acc[mt][nt][j];
        }
    }
}

// Fused GEMM: blocks [0,2048) L0, [2048,2560) L1, [2560,2688) L2 (64-row blocks)
__global__ __launch_bounds__(256, 2) void gemm_fused(
    const float* __restrict__ x0, const float* __restrict__ x1,
    const float* __restrict__ x2,
    const __bf16* __restrict__ wfb,
    __bf16* __restrict__ y0, __bf16* __restrict__ y1, __bf16* __restrict__ y2)
{
    const int b = blockIdx.x;
    if (b < 2048)       gemm_body(b,        x0, wfb,         y0);
    else if (b < 2560)  gemm_body(b - 2048, x1, wfb + 16384, y1);
    else                gemm_body(b - 2560, x2, wfb + 32768, y2);
}

// ------------------------------------------------------------------
// Projection body: per group g, neighbors nh[g][0..7]:
//   logw[p][j] = -(dlat^2+dlon_w^2)/(2 sigma^2) + kappa*(cos(dlon_w)-1)
//   w = softmax_j(logw);  out[n=g*GS+p][d] = sum_j w[p][j]*y[nh[g][j]][d]
// ------------------------------------------------------------------
template<int GS, int CG, int ROUNDS>
__device__ __forceinline__ void proj_body(
    int bid, float (*wlds)[128],
    const __bf16* __restrict__ y,      // [B*N][64] bf16
    const float* __restrict__ coords,  // [2][N]
    const int*   __restrict__ nh,      // [N][8]
    const float* __restrict__ oc,      // [2][B][N0]
    const float* __restrict__ sig_p,
    const float* __restrict__ kap_p,
    float* __restrict__ out,           // [B][N0][64]
    int N, int N0)
{
    constexpr int B = 2;
    static_assert(CG * GS == ROUNDS * 8, "slot layout");

    const int wslot = threadIdx.x >> 6;
    const int lane  = threadIdx.x & 63;
    const int wave  = (bid << 2) + wslot;
    const int gpb   = N / CG;
    const int b     = wave / gpb;
    const int g0    = (wave - b * gpb) * CG;

    const float sigma  = *sig_p;
    const float kappa  = *kap_p;
    const float inv2s2 = 1.0f / (2.0f * sigma * sigma);

    const int j  = lane & 7;
    const int pp = lane >> 3;

    #pragma unroll
    for (int r = 0; r < ROUNDS; ++r) {
        const int pidx = r * 8 + pp;
        const int q = pidx / GS;
        const int p = pidx - q * GS;
        const int g = g0 + q;
        const int idx = nh[g * 8 + j];
        const float clon = coords[idx];
        const float clat = coords[N + idx];
        const int n = g * GS + p;
        const float olon = oc[(long)b * N0 + n];
        const float olat = oc[(long)(B + b) * N0 + n];

        float dlon = olon - clon;
        float t = (dlon + PI_F) * INV_TWO_PI_F;   // floor-mod wrap to [-pi, pi)
        t -= floorf(t);
        dlon = t * TWO_PI_F - PI_F;
        const float dlat = olat - clat;

        float logw = -(dlat * dlat + dlon * dlon) * inv2s2
                   + kappa * (cosf(dlon) - 1.0f);

        float m = logw;
        m = fmaxf(m, __shfl_xor(m, 1));
        m = fmaxf(m, __shfl_xor(m, 2));
        m = fmaxf(m, __shfl_xor(m, 4));
        float e = expf(logw - m);
        float s = e;
        s += __shfl_xor(s, 1);
        s += __shfl_xor(s, 2);
        s += __shfl_xor(s, 4);
        wlds[wslot][r * 64 + lane] = e / s;
    }

    __syncthreads();

    const int d = lane;
    const __bf16* yb = y + (long)b * N * 64 + d;
    #pragma unroll
    for (int pidx = 0; pidx < CG * GS; ++pidx) {
        const int q = pidx / GS;
        const int p = pidx - q * GS;
        const int g = g0 + q;
        const int* nhg = nh + g * 8;
        const float* wrow = &wlds[wslot][(pidx >> 3) * 64 + (pidx & 7) * 8];
        float a = 0.0f;
        #pragma unroll
        for (int jj = 0; jj < 8; ++jj)
            a = fmaf(wrow[jj], (float)yb[(long)nhg[jj] * 64], a);
        const int n = g * GS + p;
        out[((long)b * N0 + n) * 64 + d] = a;
    }
}

// Fused projection: blocks [0,4096) L0, [4096,8192) L1, [8192,10240) L2.
__global__ __launch_bounds__(256) void proj_fused(
    const __bf16* __restrict__ y0, const __bf16* __restrict__ y1,
    const __bf16* __restrict__ y2,
    const float* __restrict__ c0, const float* __restrict__ c1,
    const float* __restrict__ c2,
    const int* __restrict__ nh0, const int* __restrict__ nh1,
    const int* __restrict__ nh2,
    const float* __restrict__ oc,
    const float* __restrict__ sig0, const float* __restrict__ sig1,
    const float* __restrict__ sig2,
    const float* __restrict__ kap0, const float* __restrict__ kap1,
    const float* __restrict__ kap2,
    float* __restrict__ out)
{
    __shared__ float wlds[4][128];
    const size_t SLICE = (size_t)2 * 65536 * 64;
    const int b = blockIdx.x;
    if (b < 4096)
        proj_body<1, 8, 1>(b, wlds, y0, c0, nh0, oc, sig0, kap0,
                           out, 65536, 65536);
    else if (b < 8192)
        proj_body<4, 2, 1>(b - 4096, wlds, y1, c1, nh1, oc, sig1, kap1,
                           out + SLICE, 16384, 65536);
    else
        proj_body<16, 1, 2>(b - 8192, wlds, y2, c2, nh2, oc, sig2, kap2,
                            out + 2 * SLICE, 4096, 65536);
}

// ------------------------------------------------------------------
extern "C" void kernel_launch(void* const* d_in, const int* in_sizes, int n_in,
                              void* d_out, int out_size, void* d_ws, size_t ws_size,
                              hipStream_t stream)
{
    const float* x0   = (const float*)d_in[0];
    const float* x1   = (const float*)d_in[1];
    const float* x2   = (const float*)d_in[2];
    const float* W0   = (const float*)d_in[3];
    const float* W1   = (const float*)d_in[4];
    const float* W2   = (const float*)d_in[5];
    const float* sig0 = (const float*)d_in[6];
    const float* sig1 = (const float*)d_in[7];
    const float* sig2 = (const float*)d_in[8];
    const float* kap0 = (const float*)d_in[9];
    const float* kap1 = (const float*)d_in[10];
    const float* kap2 = (const float*)d_in[11];
    const float* c0   = (const float*)d_in[12];
    const float* c1   = (const float*)d_in[13];
    const float* c2   = (const float*)d_in[14];
    const int*   nh0  = (const int*)d_in[15];
    const int*   nh1  = (const int*)d_in[16];
    const int*   nh2  = (const int*)d_in[17];
    const float* oc   = (const float*)d_in[18];

    float* out = (float*)d_out;
    // d_ws layout (bf16 elements): wfb[3*16384] | y0 | y1 | y2
    __bf16* wfb = (__bf16*)d_ws;
    __bf16* y0  = wfb + 3 * 16384;
    __bf16* y1  = y0 + (size_t)2 * 65536 * 64;
    __bf16* y2  = y1 + (size_t)2 * 16384 * 64;

    wprep<<<24, 256, 0, stream>>>(W0, W1, W2, wfb);
    gemm_fused<<<2688, 256, 0, stream>>>(x0, x1, x2, wfb, y0, y1, y2);
    proj_fused<<<10240, 256, 0, stream>>>(y0, y1, y2, c0, c1, c2,
                                          nh0, nh1, nh2, oc,
                                          sig0, sig1, sig2,
                                          kap0, kap1, kap2, out);
}